// Round 2
// baseline (362.573 us; speedup 1.0000x reference)
//
#include <hip/hip_runtime.h>
#include <hip/hip_bf16.h>

using short8 = __attribute__((ext_vector_type(8))) short;
using f32x4  = __attribute__((ext_vector_type(4))) float;

#define T_SEQ  2048
#define C_DIM  2048
#define NH     32
#define NKV    8
#define HD     64
#define WINDOW 512
#define NGLOB  16

__device__ inline ushort f2bf(float f) {
  union { float f; unsigned u; } v; v.f = f;
  unsigned u = v.u;
  u += 0x7fffu + ((u >> 16) & 1u);
  return (ushort)(u >> 16);
}
__device__ inline float bf2f(ushort h) {
  union { unsigned u; float f; } v; v.u = ((unsigned)h) << 16;
  return v.f;
}

// C[M,N] = A[M,K] @ B[N,K]^T. AF/BF: operand is f32 (else bf16 ushort).
// CF: write f32 (else bf16). f32 operands are converted to bf16 during staging.
// 128x128 tile, 4 waves (each 64x64), BK=32.
template <bool AF, bool BF, bool CF>
__global__ __launch_bounds__(256) void gemm_bt(const void* __restrict__ Ap,
                                               const void* __restrict__ Bp,
                                               void* __restrict__ Cp,
                                               int M, int N, int K) {
  __shared__ ushort As[128][40];   // +8 pad: row stride 80B -> <=2-way bank alias
  __shared__ ushort Bs[128][40];
  const int tid  = threadIdx.x;
  const int lane = tid & 63;
  const int w    = tid >> 6;
  const int wr   = w >> 1, wc = w & 1;
  const int tileM = blockIdx.y * 128, tileN = blockIdx.x * 128;
  const int r16 = lane & 15, g16 = lane >> 4;

  f32x4 acc[4][4];
#pragma unroll
  for (int i = 0; i < 4; i++)
#pragma unroll
    for (int j = 0; j < 4; j++) acc[i][j] = (f32x4){0.f, 0.f, 0.f, 0.f};

  for (int k0 = 0; k0 < K; k0 += 32) {
#pragma unroll
    for (int s = 0; s < 2; s++) {
      int idx = tid + s * 256;            // 512 8-elem chunks: 128 rows x 4 chunks
      int row = idx >> 2, c8 = idx & 3;
      size_t aoff = (size_t)(tileM + row) * K + k0 + c8 * 8;
      short8 av;
      if constexpr (AF) {
        const float* A = (const float*)Ap;
        f32x4 lo = *reinterpret_cast<const f32x4*>(&A[aoff]);
        f32x4 hi = *reinterpret_cast<const f32x4*>(&A[aoff + 4]);
#pragma unroll
        for (int j = 0; j < 4; j++) { av[j] = (short)f2bf(lo[j]); av[4 + j] = (short)f2bf(hi[j]); }
      } else {
        av = *reinterpret_cast<const short8*>(&((const ushort*)Ap)[aoff]);
      }
      *reinterpret_cast<short8*>(&As[row][c8 * 8]) = av;

      size_t boff = (size_t)(tileN + row) * K + k0 + c8 * 8;
      short8 bv;
      if constexpr (BF) {
        const float* B = (const float*)Bp;
        f32x4 lo = *reinterpret_cast<const f32x4*>(&B[boff]);
        f32x4 hi = *reinterpret_cast<const f32x4*>(&B[boff + 4]);
#pragma unroll
        for (int j = 0; j < 4; j++) { bv[j] = (short)f2bf(lo[j]); bv[4 + j] = (short)f2bf(hi[j]); }
      } else {
        bv = *reinterpret_cast<const short8*>(&((const ushort*)Bp)[boff]);
      }
      *reinterpret_cast<short8*>(&Bs[row][c8 * 8]) = bv;
    }
    __syncthreads();
    short8 af[4], bfr[4];
#pragma unroll
    for (int i = 0; i < 4; i++)
      af[i] = *reinterpret_cast<const short8*>(&As[wr * 64 + i * 16 + r16][g16 * 8]);
#pragma unroll
    for (int j = 0; j < 4; j++)
      bfr[j] = *reinterpret_cast<const short8*>(&Bs[wc * 64 + j * 16 + r16][g16 * 8]);
#pragma unroll
    for (int i = 0; i < 4; i++)
#pragma unroll
      for (int j = 0; j < 4; j++)
        acc[i][j] = __builtin_amdgcn_mfma_f32_16x16x32_bf16(af[i], bfr[j], acc[i][j], 0, 0, 0);
    __syncthreads();
  }

#pragma unroll
  for (int i = 0; i < 4; i++)
#pragma unroll
    for (int j = 0; j < 4; j++) {
      int col = tileN + wc * 64 + j * 16 + r16;
#pragma unroll
      for (int r = 0; r < 4; r++) {
        int row = tileM + wr * 64 + i * 16 + g16 * 4 + r;
        if constexpr (CF) ((float*)Cp)[(size_t)row * N + col] = acc[i][j][r];
        else              ((ushort*)Cp)[(size_t)row * N + col] = f2bf(acc[i][j][r]);
      }
    }
}

// In-place interleaved RoPE on bf16 buffer; cos/sin tables are f32.
__global__ void rope_kernel(ushort* __restrict__ X, const float* __restrict__ fc,
                            const float* __restrict__ fs, int nheads) {
  int idx = blockIdx.x * blockDim.x + threadIdx.x;   // (t, h, i)
  int total = T_SEQ * nheads * 32;
  if (idx >= total) return;
  int i = idx & 31;
  int h = (idx >> 5) % nheads;
  int t = idx / (32 * nheads);
  int ld = nheads * HD;
  size_t base = (size_t)t * ld + h * HD + 2 * i;
  float x0 = bf2f(X[base]), x1 = bf2f(X[base + 1]);
  float c = fc[t * 32 + i], s = fs[t * 32 + i];
  X[base]     = f2bf(x0 * c - x1 * s);
  X[base + 1] = f2bf(x0 * s + x1 * c);
}

// out[c][r] = in[r][c], 64x64 LDS tiles, bf16.
__global__ __launch_bounds__(256) void transpose_bf16(const ushort* __restrict__ in,
                                                      ushort* __restrict__ out,
                                                      int R, int Cc) {
  __shared__ ushort tile[64][72];
  int tr = blockIdx.y * 64, tc = blockIdx.x * 64;
  int tid = threadIdx.x;
#pragma unroll
  for (int s = 0; s < 2; s++) {
    int idx = tid + s * 256;
    int row = idx >> 3, c8 = idx & 7;
    short8 v = *reinterpret_cast<const short8*>(&in[(size_t)(tr + row) * Cc + tc + c8 * 8]);
#pragma unroll
    for (int j = 0; j < 8; j++) tile[row][c8 * 8 + j] = (ushort)v[j];
  }
  __syncthreads();
#pragma unroll
  for (int s = 0; s < 2; s++) {
    int idx = tid + s * 256;
    int orow = idx >> 3, c8 = idx & 7;
    short8 v;
#pragma unroll
    for (int j = 0; j < 8; j++) v[j] = (short)tile[c8 * 8 + j][orow];
    *reinterpret_cast<short8*>(&out[(size_t)(tc + orow) * R + tr + c8 * 8]) = v;
  }
}

// Flash attention: 1 wave per (q-head, 16-row q tile). Key blocks of 32.
// Q:(T, 2048) rope'd bf16, K:(T, 512) rope'd bf16, Vt:(512, T) bf16. Y:(T, 2048) bf16.
__global__ __launch_bounds__(256) void attn_kernel(const ushort* __restrict__ Q,
                                                   const ushort* __restrict__ K,
                                                   const ushort* __restrict__ Vt,
                                                   ushort* __restrict__ Y) {
  __shared__ ushort Plds[4][16][40];
  const int lane = threadIdx.x & 63;
  const int wv   = threadIdx.x >> 6;
  const int task = blockIdx.x * 4 + wv;      // 4096 tasks
  const int h  = task >> 7;                  // 0..31 q-head
  const int qt = task & 127;
  const int q0 = qt << 4;
  const int g  = h >> 2;                     // kv head
  const int r16 = lane & 15, g16 = lane >> 4;

  const short8 qf0 = *reinterpret_cast<const short8*>(&Q[(size_t)(q0 + r16) * C_DIM + h * HD + g16 * 8]);
  const short8 qf1 = *reinterpret_cast<const short8*>(&Q[(size_t)(q0 + r16) * C_DIM + h * HD + 32 + g16 * 8]);

  float m[4], ssum[4];
  f32x4 accy[4];
#pragma unroll
  for (int r = 0; r < 4; r++) { m[r] = -INFINITY; ssum[r] = 0.f; }
#pragma unroll
  for (int n = 0; n < 4; n++) accy[n] = (f32x4){0.f, 0.f, 0.f, 0.f};

  int kb0 = q0 - (WINDOW - 1); if (kb0 < 0) kb0 = 0;
  kb0 = (kb0 >> 5) << 5;
  int nwin = (q0 + 16 - kb0 + 31) >> 5;
  int nblk = nwin + (kb0 > 0 ? 1 : 0);       // extra leading iteration = global block

  for (int bi = 0; bi < nblk; bi++) {
    int kb;
    if (kb0 > 0) kb = (bi == 0) ? 0 : kb0 + (bi - 1) * 32;
    else         kb = bi * 32;

    // S = Q K^T for 16 q-rows x 32 keys
    f32x4 sc[2] = { (f32x4){0.f,0.f,0.f,0.f}, (f32x4){0.f,0.f,0.f,0.f} };
#pragma unroll
    for (int c = 0; c < 2; c++) {
      const ushort* kp = &K[(size_t)(kb + c * 16 + r16) * (NKV * HD) + g * HD + g16 * 8];
      short8 kf0 = *reinterpret_cast<const short8*>(kp);
      short8 kf1 = *reinterpret_cast<const short8*>(kp + 32);
      sc[c] = __builtin_amdgcn_mfma_f32_16x16x32_bf16(qf0, kf0, sc[c], 0, 0, 0);
      sc[c] = __builtin_amdgcn_mfma_f32_16x16x32_bf16(qf1, kf1, sc[c], 0, 0, 0);
    }

    // online softmax update (rows live in 16-lane groups: row = q0 + g16*4 + r)
    float p[2][4];
#pragma unroll
    for (int r = 0; r < 4; r++) {
      int row = q0 + g16 * 4 + r;
      int col0 = kb + r16, col1 = kb + 16 + r16;
      bool v0 = ((col0 <= row) && (col0 >= row - (WINDOW - 1))) || (col0 < NGLOB);
      bool v1 = ((col1 <= row) && (col1 >= row - (WINDOW - 1))) || (col1 < NGLOB);
      float s0 = v0 ? sc[0][r] * 0.125f : -INFINITY;
      float s1 = v1 ? sc[1][r] * 0.125f : -INFINITY;
      p[0][r] = s0; p[1][r] = s1;
      float loc = fmaxf(s0, s1);
      loc = fmaxf(loc, __shfl_xor(loc, 1));
      loc = fmaxf(loc, __shfl_xor(loc, 2));
      loc = fmaxf(loc, __shfl_xor(loc, 4));
      loc = fmaxf(loc, __shfl_xor(loc, 8));
      float mn = fmaxf(m[r], loc);
      float corr = (mn == -INFINITY) ? 1.0f : __expf(m[r] - mn);
      float p0 = (mn == -INFINITY) ? 0.0f : __expf(p[0][r] - mn);
      float p1 = (mn == -INFINITY) ? 0.0f : __expf(p[1][r] - mn);
      float psum = p0 + p1;
      psum += __shfl_xor(psum, 1);
      psum += __shfl_xor(psum, 2);
      psum += __shfl_xor(psum, 4);
      psum += __shfl_xor(psum, 8);
      ssum[r] = ssum[r] * corr + psum;
      m[r] = mn;
#pragma unroll
      for (int n = 0; n < 4; n++) accy[n][r] *= corr;
      Plds[wv][g16 * 4 + r][r16]      = f2bf(p0);
      Plds[wv][g16 * 4 + r][16 + r16] = f2bf(p1);
    }

    // P fragment (A layout) from LDS, then Y += P @ V
    short8 pf = *reinterpret_cast<const short8*>(&Plds[wv][r16][g16 * 8]);
#pragma unroll
    for (int n = 0; n < 4; n++) {
      short8 vf = *reinterpret_cast<const short8*>(
          &Vt[(size_t)(g * HD + n * 16 + r16) * T_SEQ + kb + g16 * 8]);
      accy[n] = __builtin_amdgcn_mfma_f32_16x16x32_bf16(pf, vf, accy[n], 0, 0, 0);
    }
  }

#pragma unroll
  for (int n = 0; n < 4; n++)
#pragma unroll
    for (int r = 0; r < 4; r++) {
      int row = q0 + g16 * 4 + r;
      Y[(size_t)row * C_DIM + h * HD + n * 16 + r16] = f2bf(accy[n][r] / ssum[r]);
    }
}

extern "C" void kernel_launch(void* const* d_in, const int* in_sizes, int n_in,
                              void* d_out, int out_size, void* d_ws, size_t ws_size,
                              hipStream_t stream) {
  const void*  x  = d_in[0];                 // f32 (2048, 2048)
  const float* fc = (const float*)d_in[1];   // f32 (2048, 32)
  const float* fs = (const float*)d_in[2];   // f32 (2048, 32)
  const void*  wq = d_in[3];                 // f32 (2048, 2048)
  const void*  wk = d_in[4];                 // f32 (512, 2048)
  const void*  wv = d_in[5];                 // f32 (512, 2048)
  const void*  wo = d_in[6];                 // f32 (2048, 2048)
  float* out = (float*)d_out;                // f32 (2048, 2048)

  ushort* Qb = (ushort*)d_ws;                       // 2048x2048 bf16
  ushort* Kb = Qb + (size_t)T_SEQ * C_DIM;          // 2048x512
  ushort* Vb = Kb + (size_t)T_SEQ * (NKV * HD);     // 2048x512
  ushort* Vt = Vb + (size_t)T_SEQ * (NKV * HD);     // 512x2048
  ushort* Yb = Vt + (size_t)T_SEQ * (NKV * HD);     // 2048x2048

  dim3 blk(256);
  gemm_bt<true, true, false><<<dim3(16, 16), blk, 0, stream>>>(x, wq, Qb, T_SEQ, C_DIM, C_DIM);
  gemm_bt<true, true, false><<<dim3(4, 16),  blk, 0, stream>>>(x, wk, Kb, T_SEQ, NKV * HD, C_DIM);
  gemm_bt<true, true, false><<<dim3(4, 16),  blk, 0, stream>>>(x, wv, Vb, T_SEQ, NKV * HD, C_DIM);
  rope_kernel<<<(T_SEQ * NH * 32 + 255) / 256, blk, 0, stream>>>(Qb, fc, fs, NH);
  rope_kernel<<<(T_SEQ * NKV * 32 + 255) / 256, blk, 0, stream>>>(Kb, fc, fs, NKV);
  transpose_bf16<<<dim3((NKV * HD) / 64, T_SEQ / 64), blk, 0, stream>>>(Vb, Vt, T_SEQ, NKV * HD);
  attn_kernel<<<1024, blk, 0, stream>>>(Qb, Kb, Vt, Yb);
  gemm_bt<false, true, true><<<dim3(16, 16), blk, 0, stream>>>(Yb, wo, out, T_SEQ, C_DIM, C_DIM);
}

// Round 3
// 177.018 us; speedup vs baseline: 2.0482x; 2.0482x over previous
//
#include <hip/hip_runtime.h>
#include <hip/hip_bf16.h>

using short8 = __attribute__((ext_vector_type(8))) short;
using f32x4  = __attribute__((ext_vector_type(4))) float;

#define T_SEQ  2048
#define C_DIM  2048
#define NH     32
#define NKV    8
#define HD     64
#define WINDOW 512
#define NGLOB  16

__device__ inline ushort f2bf(float f) {
  union { float f; unsigned u; } v; v.f = f;
  unsigned u = v.u;
  u += 0x7fffu + ((u >> 16) & 1u);
  return (ushort)(u >> 16);
}
__device__ inline float bf2f(ushort h) {
  union { unsigned u; float f; } v; v.u = ((unsigned)h) << 16;
  return v.f;
}

__device__ __forceinline__ void gl_lds16(const ushort* g, ushort* l) {
  __builtin_amdgcn_global_load_lds(
      (const __attribute__((address_space(1))) void*)g,
      (__attribute__((address_space(3))) void*)l, 16, 0, 0);
}

// f32 -> bf16 convert, 8 elems/thread, grid-stride.
__global__ void cvt_f32_bf16(const float* __restrict__ in, ushort* __restrict__ out, int n8) {
  int i = blockIdx.x * blockDim.x + threadIdx.x;
  int stride = gridDim.x * blockDim.x;
  for (; i < n8; i += stride) {
    f32x4 a = *reinterpret_cast<const f32x4*>(in + (size_t)i * 8);
    f32x4 b = *reinterpret_cast<const f32x4*>(in + (size_t)i * 8 + 4);
    short8 o;
#pragma unroll
    for (int j = 0; j < 4; j++) { o[j] = (short)f2bf(a[j]); o[4 + j] = (short)f2bf(b[j]); }
    *reinterpret_cast<short8*>(out + (size_t)i * 8) = o;
  }
}

// 2-phase double-buffered bf16 GEMM, C = A @ B^T.
// 128x128 tile, BK=64, 512 threads (8 waves, 2Mx4N), global_load_lds staging,
// chunk-XOR LDS swizzle (inverse-swizzled global source, swizzled ds_read).
// MODE 0: plain, B0/C0, f32 out (O-projection).
// MODE 1: fused QKV, region select over bx, bf16 out.
template <int MODE>
__global__ __launch_bounds__(512) void gemm2p(const ushort* __restrict__ A,
                                              const ushort* __restrict__ B0,
                                              const ushort* __restrict__ B1,
                                              const ushort* __restrict__ B2,
                                              void* __restrict__ C0,
                                              void* __restrict__ C1,
                                              void* __restrict__ C2,
                                              int K) {
  __shared__ ushort As[2][2][128][32];   // [dbuf][k-half][row][col]
  __shared__ ushort Bs[2][2][128][32];
  const int tid  = threadIdx.x;
  const int lane = tid & 63;
  const int wid  = tid >> 6;
  const int wr = wid >> 2, wc = wid & 3;           // 2M x 4N waves, each 64x32
  const int r16 = lane & 15, g16 = (lane >> 4) & 3;
  const int bx = blockIdx.x, by = blockIdx.y;

  const ushort* Brow;
  void* Cout;
  int ldc, col0;
  if constexpr (MODE == 1) {
    if (bx < 16)      { Brow = B0 + (size_t)bx * 128 * K;        Cout = C0; ldc = 2048; col0 = bx * 128; }
    else if (bx < 20) { Brow = B1 + (size_t)(bx - 16) * 128 * K; Cout = C1; ldc = 512;  col0 = (bx - 16) * 128; }
    else              { Brow = B2 + (size_t)(bx - 20) * 128 * K; Cout = C2; ldc = 512;  col0 = (bx - 20) * 128; }
  } else {
    Brow = B0 + (size_t)bx * 128 * K; Cout = C0; ldc = 2048; col0 = bx * 128;
  }
  const ushort* Arow = A + (size_t)by * 128 * K;

  f32x4 acc[4][2];
#pragma unroll
  for (int i = 0; i < 4; i++)
#pragma unroll
    for (int j = 0; j < 2; j++) acc[i][j] = (f32x4){0.f, 0.f, 0.f, 0.f};

  // staging map: thread -> (row, chunk); source chunk inverse-swizzled
  const int srow = tid >> 2, scch = tid & 3;
  const int ssc  = scch ^ ((srow >> 1) & 3);
  const size_t agoff = (size_t)srow * K + ssc * 8;
  // fragment-read chunk (swizzled); constant per lane since row ^ r16 keeps (row>>1)&3
  const int rchunk = (g16 ^ ((r16 >> 1) & 3)) * 8;

  const int nt = K >> 6;
  int d = 0;

#define STAGE(dd, k0)                                                         \
  {                                                                           \
    _Pragma("unroll") for (int kk = 0; kk < 2; kk++) {                        \
      gl_lds16(&Arow[agoff + (k0) + kk * 32], &As[dd][kk][srow][scch * 8]);   \
      gl_lds16(&Brow[agoff + (k0) + kk * 32], &Bs[dd][kk][srow][scch * 8]);   \
    }                                                                         \
  }

  STAGE(0, 0);
  __syncthreads();

  for (int t = 0; t < nt; ++t) {
    if (t + 1 < nt) STAGE(d ^ 1, (t + 1) * 64);
#pragma unroll
    for (int kk = 0; kk < 2; kk++) {
      short8 af[4], bfv[2];
#pragma unroll
      for (int i = 0; i < 4; i++)
        af[i] = *reinterpret_cast<const short8*>(&As[d][kk][wr * 64 + i * 16 + r16][rchunk]);
#pragma unroll
      for (int j = 0; j < 2; j++)
        bfv[j] = *reinterpret_cast<const short8*>(&Bs[d][kk][wc * 32 + j * 16 + r16][rchunk]);
#pragma unroll
      for (int i = 0; i < 4; i++)
#pragma unroll
        for (int j = 0; j < 2; j++)
          acc[i][j] = __builtin_amdgcn_mfma_f32_16x16x32_bf16(af[i], bfv[j], acc[i][j], 0, 0, 0);
    }
    __syncthreads();
    d ^= 1;
  }
#undef STAGE

#pragma unroll
  for (int i = 0; i < 4; i++)
#pragma unroll
    for (int j = 0; j < 2; j++) {
      int col = col0 + wc * 32 + j * 16 + r16;
#pragma unroll
      for (int r = 0; r < 4; r++) {
        int row = by * 128 + wr * 64 + i * 16 + g16 * 4 + r;
        if constexpr (MODE == 0) ((float*)Cout)[(size_t)row * ldc + col] = acc[i][j][r];
        else                     ((ushort*)Cout)[(size_t)row * ldc + col] = f2bf(acc[i][j][r]);
      }
    }
}

// In-place interleaved RoPE on bf16 buffer; cos/sin tables are f32.
__global__ void rope_kernel(ushort* __restrict__ X, const float* __restrict__ fc,
                            const float* __restrict__ fs, int nheads) {
  int idx = blockIdx.x * blockDim.x + threadIdx.x;   // (t, h, i)
  int total = T_SEQ * nheads * 32;
  if (idx >= total) return;
  int i = idx & 31;
  int h = (idx >> 5) % nheads;
  int t = idx / (32 * nheads);
  int ld = nheads * HD;
  size_t base = (size_t)t * ld + h * HD + 2 * i;
  float x0 = bf2f(X[base]), x1 = bf2f(X[base + 1]);
  float c = fc[t * 32 + i], s = fs[t * 32 + i];
  X[base]     = f2bf(x0 * c - x1 * s);
  X[base + 1] = f2bf(x0 * s + x1 * c);
}

// out[c][r] = in[r][c], 64x64 LDS tiles, bf16.
__global__ __launch_bounds__(256) void transpose_bf16(const ushort* __restrict__ in,
                                                      ushort* __restrict__ out,
                                                      int R, int Cc) {
  __shared__ ushort tile[64][72];
  int tr = blockIdx.y * 64, tc = blockIdx.x * 64;
  int tid = threadIdx.x;
#pragma unroll
  for (int s = 0; s < 2; s++) {
    int idx = tid + s * 256;
    int row = idx >> 3, c8 = idx & 7;
    short8 v = *reinterpret_cast<const short8*>(&in[(size_t)(tr + row) * Cc + tc + c8 * 8]);
#pragma unroll
    for (int j = 0; j < 8; j++) tile[row][c8 * 8 + j] = (ushort)v[j];
  }
  __syncthreads();
#pragma unroll
  for (int s = 0; s < 2; s++) {
    int idx = tid + s * 256;
    int orow = idx >> 3, c8 = idx & 7;
    short8 v;
#pragma unroll
    for (int j = 0; j < 8; j++) v[j] = (short)tile[c8 * 8 + j][orow];
    *reinterpret_cast<short8*>(&out[(size_t)(tc + orow) * R + tr + c8 * 8]) = v;
  }
}

// Flash attention: 1 wave per (q-head, 16-row q tile). Key blocks of 32.
__global__ __launch_bounds__(256) void attn_kernel(const ushort* __restrict__ Q,
                                                   const ushort* __restrict__ K,
                                                   const ushort* __restrict__ Vt,
                                                   ushort* __restrict__ Y) {
  __shared__ ushort Plds[4][16][40];
  const int lane = threadIdx.x & 63;
  const int wv   = threadIdx.x >> 6;
  const int task = blockIdx.x * 4 + wv;      // 4096 tasks
  const int h  = task >> 7;                  // 0..31 q-head
  const int qt = task & 127;
  const int q0 = qt << 4;
  const int g  = h >> 2;                     // kv head
  const int r16 = lane & 15, g16 = lane >> 4;

  const short8 qf0 = *reinterpret_cast<const short8*>(&Q[(size_t)(q0 + r16) * C_DIM + h * HD + g16 * 8]);
  const short8 qf1 = *reinterpret_cast<const short8*>(&Q[(size_t)(q0 + r16) * C_DIM + h * HD + 32 + g16 * 8]);

  float m[4], ssum[4];
  f32x4 accy[4];
#pragma unroll
  for (int r = 0; r < 4; r++) { m[r] = -INFINITY; ssum[r] = 0.f; }
#pragma unroll
  for (int n = 0; n < 4; n++) accy[n] = (f32x4){0.f, 0.f, 0.f, 0.f};

  int kb0 = q0 - (WINDOW - 1); if (kb0 < 0) kb0 = 0;
  kb0 = (kb0 >> 5) << 5;
  int nwin = (q0 + 16 - kb0 + 31) >> 5;
  int nblk = nwin + (kb0 > 0 ? 1 : 0);       // extra leading iteration = global block

  for (int bi = 0; bi < nblk; bi++) {
    int kb;
    if (kb0 > 0) kb = (bi == 0) ? 0 : kb0 + (bi - 1) * 32;
    else         kb = bi * 32;

    f32x4 sc[2] = { (f32x4){0.f,0.f,0.f,0.f}, (f32x4){0.f,0.f,0.f,0.f} };
#pragma unroll
    for (int c = 0; c < 2; c++) {
      const ushort* kp = &K[(size_t)(kb + c * 16 + r16) * (NKV * HD) + g * HD + g16 * 8];
      short8 kf0 = *reinterpret_cast<const short8*>(kp);
      short8 kf1 = *reinterpret_cast<const short8*>(kp + 32);
      sc[c] = __builtin_amdgcn_mfma_f32_16x16x32_bf16(qf0, kf0, sc[c], 0, 0, 0);
      sc[c] = __builtin_amdgcn_mfma_f32_16x16x32_bf16(qf1, kf1, sc[c], 0, 0, 0);
    }

    float p[2][4];
#pragma unroll
    for (int r = 0; r < 4; r++) {
      int row = q0 + g16 * 4 + r;
      int col0 = kb + r16, col1 = kb + 16 + r16;
      bool v0 = ((col0 <= row) && (col0 >= row - (WINDOW - 1))) || (col0 < NGLOB);
      bool v1 = ((col1 <= row) && (col1 >= row - (WINDOW - 1))) || (col1 < NGLOB);
      float s0 = v0 ? sc[0][r] * 0.125f : -INFINITY;
      float s1 = v1 ? sc[1][r] * 0.125f : -INFINITY;
      p[0][r] = s0; p[1][r] = s1;
      float loc = fmaxf(s0, s1);
      loc = fmaxf(loc, __shfl_xor(loc, 1));
      loc = fmaxf(loc, __shfl_xor(loc, 2));
      loc = fmaxf(loc, __shfl_xor(loc, 4));
      loc = fmaxf(loc, __shfl_xor(loc, 8));
      float mn = fmaxf(m[r], loc);
      float corr = (mn == -INFINITY) ? 1.0f : __expf(m[r] - mn);
      float p0 = (mn == -INFINITY) ? 0.0f : __expf(p[0][r] - mn);
      float p1 = (mn == -INFINITY) ? 0.0f : __expf(p[1][r] - mn);
      float psum = p0 + p1;
      psum += __shfl_xor(psum, 1);
      psum += __shfl_xor(psum, 2);
      psum += __shfl_xor(psum, 4);
      psum += __shfl_xor(psum, 8);
      ssum[r] = ssum[r] * corr + psum;
      m[r] = mn;
#pragma unroll
      for (int n = 0; n < 4; n++) accy[n][r] *= corr;
      Plds[wv][g16 * 4 + r][r16]      = f2bf(p0);
      Plds[wv][g16 * 4 + r][16 + r16] = f2bf(p1);
    }

    short8 pf = *reinterpret_cast<const short8*>(&Plds[wv][r16][g16 * 8]);
#pragma unroll
    for (int n = 0; n < 4; n++) {
      short8 vf = *reinterpret_cast<const short8*>(
          &Vt[(size_t)(g * HD + n * 16 + r16) * T_SEQ + kb + g16 * 8]);
      accy[n] = __builtin_amdgcn_mfma_f32_16x16x32_bf16(pf, vf, accy[n], 0, 0, 0);
    }
  }

#pragma unroll
  for (int n = 0; n < 4; n++)
#pragma unroll
    for (int r = 0; r < 4; r++) {
      int row = q0 + g16 * 4 + r;
      Y[(size_t)row * C_DIM + h * HD + n * 16 + r16] = f2bf(accy[n][r] / ssum[r]);
    }
}

extern "C" void kernel_launch(void* const* d_in, const int* in_sizes, int n_in,
                              void* d_out, int out_size, void* d_ws, size_t ws_size,
                              hipStream_t stream) {
  const float* x  = (const float*)d_in[0];   // (2048, 2048)
  const float* fc = (const float*)d_in[1];   // (2048, 32)
  const float* fs = (const float*)d_in[2];   // (2048, 32)
  const float* wq = (const float*)d_in[3];   // (2048, 2048)
  const float* wk = (const float*)d_in[4];   // (512, 2048)
  const float* wv = (const float*)d_in[5];   // (512, 2048)
  const float* wo = (const float*)d_in[6];   // (2048, 2048)
  float* out = (float*)d_out;                // (2048, 2048)

  const size_t SZ_X = (size_t)T_SEQ * C_DIM;        // 4M
  const size_t SZ_W = (size_t)(NKV * HD) * C_DIM;   // 1M

  ushort* xb  = (ushort*)d_ws;
  ushort* wqb = xb  + SZ_X;
  ushort* wkb = wqb + SZ_X;
  ushort* wvb = wkb + SZ_W;
  ushort* wob = wvb + SZ_W;
  ushort* Qb  = wob + SZ_X;
  ushort* Kb  = Qb  + SZ_X;
  ushort* Vb  = Kb  + SZ_W;
  ushort* Vt  = Vb  + SZ_W;
  ushort* Yb  = Vt  + SZ_W;

  // converts
  cvt_f32_bf16<<<512, 256, 0, stream>>>(x,  xb,  (int)(SZ_X / 8));
  cvt_f32_bf16<<<512, 256, 0, stream>>>(wq, wqb, (int)(SZ_X / 8));
  cvt_f32_bf16<<<256, 256, 0, stream>>>(wk, wkb, (int)(SZ_W / 8));
  cvt_f32_bf16<<<256, 256, 0, stream>>>(wv, wvb, (int)(SZ_W / 8));
  cvt_f32_bf16<<<512, 256, 0, stream>>>(wo, wob, (int)(SZ_X / 8));

  // fused QKV projection: 24 col-tiles (16 Q, 4 K, 4 V) x 16 row-tiles
  gemm2p<1><<<dim3(24, 16), 512, 0, stream>>>(xb, wqb, wkb, wvb, Qb, Kb, Vb, C_DIM);

  rope_kernel<<<(T_SEQ * NH * 32 + 255) / 256, 256, 0, stream>>>(Qb, fc, fs, NH);
  rope_kernel<<<(T_SEQ * NKV * 32 + 255) / 256, 256, 0, stream>>>(Kb, fc, fs, NKV);
  transpose_bf16<<<dim3((NKV * HD) / 64, T_SEQ / 64), 256, 0, stream>>>(Vb, Vt, T_SEQ, NKV * HD);
  attn_kernel<<<1024, 256, 0, stream>>>(Qb, Kb, Vt, Yb);

  // output projection, f32 out
  gemm2p<0><<<dim3(16, 16), 512, 0, stream>>>(Yb, wob, nullptr, nullptr, out, nullptr, nullptr, C_DIM);
}

// Round 5
// 142.431 us; speedup vs baseline: 2.5456x; 1.2428x over previous
//
#include <hip/hip_runtime.h>
#include <hip/hip_bf16.h>

using short8 = __attribute__((ext_vector_type(8))) short;
using f32x4  = __attribute__((ext_vector_type(4))) float;
using f32x16 = __attribute__((ext_vector_type(16))) float;
using int4v  = __attribute__((ext_vector_type(4))) int;

#define T_SEQ  2048
#define C_DIM  2048
#define NH     32
#define NKV    8
#define HD     64
#define WINDOW 512
#define NGLOB  16

__device__ inline ushort f2bf(float f) {
  union { float f; unsigned u; } v; v.f = f;
  unsigned u = v.u;
  u += 0x7fffu + ((u >> 16) & 1u);
  return (ushort)(u >> 16);
}
__device__ inline float bf2f(ushort h) {
  union { unsigned u; float f; } v; v.u = ((unsigned)h) << 16;
  return v.f;
}

__device__ __forceinline__ void gl_lds16(const ushort* g, ushort* l) {
  __builtin_amdgcn_global_load_lds(
      (const __attribute__((address_space(1))) void*)g,
      (__attribute__((address_space(3))) void*)l, 16, 0, 0);
}

__device__ __forceinline__ f32x16 zero16() {
  f32x16 v;
#pragma unroll
  for (int i = 0; i < 16; i++) v[i] = 0.f;
  return v;
}

// f32 -> bf16 convert, 8 elems/thread, grid-stride.
__global__ void cvt_f32_bf16(const float* __restrict__ in, ushort* __restrict__ out, int n8) {
  int i = blockIdx.x * blockDim.x + threadIdx.x;
  int stride = gridDim.x * blockDim.x;
  for (; i < n8; i += stride) {
    f32x4 a = *reinterpret_cast<const f32x4*>(in + (size_t)i * 8);
    f32x4 b = *reinterpret_cast<const f32x4*>(in + (size_t)i * 8 + 4);
    short8 o;
#pragma unroll
    for (int j = 0; j < 4; j++) { o[j] = (short)f2bf(a[j]); o[4 + j] = (short)f2bf(b[j]); }
    *reinterpret_cast<short8*>(out + (size_t)i * 8) = o;
  }
}

// 2-phase double-buffered bf16 GEMM, C = A @ B^T. (unchanged)
template <int MODE>
__global__ __launch_bounds__(512) void gemm2p(const ushort* __restrict__ A,
                                              const ushort* __restrict__ B0,
                                              const ushort* __restrict__ B1,
                                              const ushort* __restrict__ B2,
                                              void* __restrict__ C0,
                                              void* __restrict__ C1,
                                              void* __restrict__ C2,
                                              int K) {
  __shared__ ushort As[2][2][128][32];
  __shared__ ushort Bs[2][2][128][32];
  const int tid  = threadIdx.x;
  const int lane = tid & 63;
  const int wid  = tid >> 6;
  const int wr = wid >> 2, wc = wid & 3;
  const int r16 = lane & 15, g16 = (lane >> 4) & 3;
  const int bx = blockIdx.x, by = blockIdx.y;

  const ushort* Brow;
  void* Cout;
  int ldc, col0;
  if constexpr (MODE == 1) {
    if (bx < 16)      { Brow = B0 + (size_t)bx * 128 * K;        Cout = C0; ldc = 2048; col0 = bx * 128; }
    else if (bx < 20) { Brow = B1 + (size_t)(bx - 16) * 128 * K; Cout = C1; ldc = 512;  col0 = (bx - 16) * 128; }
    else              { Brow = B2 + (size_t)(bx - 20) * 128 * K; Cout = C2; ldc = 512;  col0 = (bx - 20) * 128; }
  } else {
    Brow = B0 + (size_t)bx * 128 * K; Cout = C0; ldc = 2048; col0 = bx * 128;
  }
  const ushort* Arow = A + (size_t)by * 128 * K;

  f32x4 acc[4][2];
#pragma unroll
  for (int i = 0; i < 4; i++)
#pragma unroll
    for (int j = 0; j < 2; j++) acc[i][j] = (f32x4){0.f, 0.f, 0.f, 0.f};

  const int srow = tid >> 2, scch = tid & 3;
  const int ssc  = scch ^ ((srow >> 1) & 3);
  const size_t agoff = (size_t)srow * K + ssc * 8;
  const int rchunk = (g16 ^ ((r16 >> 1) & 3)) * 8;

  const int nt = K >> 6;
  int d = 0;

#define STAGE(dd, k0)                                                         \
  {                                                                           \
    _Pragma("unroll") for (int kk = 0; kk < 2; kk++) {                        \
      gl_lds16(&Arow[agoff + (k0) + kk * 32], &As[dd][kk][srow][scch * 8]);   \
      gl_lds16(&Brow[agoff + (k0) + kk * 32], &Bs[dd][kk][srow][scch * 8]);   \
    }                                                                         \
  }

  STAGE(0, 0);
  __syncthreads();

  for (int t = 0; t < nt; ++t) {
    if (t + 1 < nt) STAGE(d ^ 1, (t + 1) * 64);
#pragma unroll
    for (int kk = 0; kk < 2; kk++) {
      short8 af[4], bfv[2];
#pragma unroll
      for (int i = 0; i < 4; i++)
        af[i] = *reinterpret_cast<const short8*>(&As[d][kk][wr * 64 + i * 16 + r16][rchunk]);
#pragma unroll
      for (int j = 0; j < 2; j++)
        bfv[j] = *reinterpret_cast<const short8*>(&Bs[d][kk][wc * 32 + j * 16 + r16][rchunk]);
#pragma unroll
      for (int i = 0; i < 4; i++)
#pragma unroll
        for (int j = 0; j < 2; j++)
          acc[i][j] = __builtin_amdgcn_mfma_f32_16x16x32_bf16(af[i], bfv[j], acc[i][j], 0, 0, 0);
    }
    __syncthreads();
    d ^= 1;
  }
#undef STAGE

#pragma unroll
  for (int i = 0; i < 4; i++)
#pragma unroll
    for (int j = 0; j < 2; j++) {
      int col = col0 + wc * 32 + j * 16 + r16;
#pragma unroll
      for (int r = 0; r < 4; r++) {
        int row = by * 128 + wr * 64 + i * 16 + g16 * 4 + r;
        if constexpr (MODE == 0) ((float*)Cout)[(size_t)row * ldc + col] = acc[i][j][r];
        else                     ((ushort*)Cout)[(size_t)row * ldc + col] = f2bf(acc[i][j][r]);
      }
    }
}

// Fused RoPE for Q and K, vectorized 8 elems (4 pairs) / thread.
__global__ void rope2(ushort* __restrict__ Qb, ushort* __restrict__ Kb,
                      const float* __restrict__ fc, const float* __restrict__ fs) {
  int idx = blockIdx.x * blockDim.x + threadIdx.x;   // chunk id
  const int QN = T_SEQ * NH * 8;
  ushort* X; int t, hh, c, ld;
  if (idx < QN) { X = Qb; c = idx & 7; hh = (idx >> 3) & 31; t = idx >> 8; ld = NH * HD; }
  else { idx -= QN; X = Kb; c = idx & 7; hh = (idx >> 3) & 7; t = idx >> 6; ld = NKV * HD; }
  size_t base = (size_t)t * ld + hh * HD + c * 8;
  short8 v = *reinterpret_cast<const short8*>(&X[base]);
  f32x4 cc = *reinterpret_cast<const f32x4*>(&fc[t * 32 + c * 4]);
  f32x4 ss = *reinterpret_cast<const f32x4*>(&fs[t * 32 + c * 4]);
  short8 o;
#pragma unroll
  for (int j = 0; j < 4; j++) {
    float x0 = bf2f((ushort)v[2 * j]), x1 = bf2f((ushort)v[2 * j + 1]);
    o[2 * j]     = (short)f2bf(x0 * cc[j] - x1 * ss[j]);
    o[2 * j + 1] = (short)f2bf(x0 * ss[j] + x1 * cc[j]);
  }
  *reinterpret_cast<short8*>(&X[base]) = o;
}

// out[c][r] = in[r][c], 64x64 LDS tiles, bf16.
__global__ __launch_bounds__(256) void transpose_bf16(const ushort* __restrict__ in,
                                                      ushort* __restrict__ out,
                                                      int R, int Cc) {
  __shared__ ushort tile[64][72];
  int tr = blockIdx.y * 64, tc = blockIdx.x * 64;
  int tid = threadIdx.x;
#pragma unroll
  for (int s = 0; s < 2; s++) {
    int idx = tid + s * 256;
    int row = idx >> 3, c8 = idx & 7;
    short8 v = *reinterpret_cast<const short8*>(&in[(size_t)(tr + row) * Cc + tc + c8 * 8]);
#pragma unroll
    for (int j = 0; j < 8; j++) tile[row][c8 * 8 + j] = (ushort)v[j];
  }
  __syncthreads();
#pragma unroll
  for (int s = 0; s < 2; s++) {
    int idx = tid + s * 256;
    int orow = idx >> 3, c8 = idx & 7;
    short8 v;
#pragma unroll
    for (int j = 0; j < 8; j++) v[j] = (short)tile[c8 * 8 + j][orow];
    *reinterpret_cast<short8*>(&out[(size_t)(tc + orow) * R + tr + c8 * 8]) = v;
  }
}

// Flash attention, swapped-operand 32x32 structure.
// 1 wave per (head, 32-row q-tile); S^T = K.Q^T; O^T = V^T.P^T; key tiles of 32.
__global__ __launch_bounds__(256) void attn32(const ushort* __restrict__ Q,
                                              const ushort* __restrict__ K,
                                              const ushort* __restrict__ Vt,
                                              ushort* __restrict__ Y) {
  __shared__ ushort Ot[4][32][72];
  const int lane = threadIdx.x & 63;
  const int wv   = threadIdx.x >> 6;
  const int h  = blockIdx.x >> 4;                    // q-head
  const int qt = ((blockIdx.x & 15) << 2) + wv;      // q-tile
  const int q0 = qt << 5;
  const int g  = h >> 2;                             // kv head
  const int l31 = lane & 31, hi = lane >> 5;
  const int hi8 = hi << 3, hi4 = hi << 2;
  const int qrow = q0 + l31;
  const float KLOG = 0.125f * 1.44269504089f;        // scale * log2(e)

  // Q B-fragments: col=q (lane-local), k-dims (hi*8 + j) per 16-dim step
  short8 qf[4];
#pragma unroll
  for (int s = 0; s < 4; s++)
    qf[s] = *reinterpret_cast<const short8*>(&Q[(size_t)qrow * C_DIM + h * HD + s * 16 + hi8]);

  f32x16 o[2] = { zero16(), zero16() };
  float mrow = -1e30f, ssum = 0.f;

  // P^T B-fragment builder. p[2i],p[2i+1] are C/D rows 2i,2i+1 = consecutive keys.
  // v_permlane32_swap_b32 vdst, vsrc: vdst.hi <-> vsrc.lo.
  //  swap(pk01, pk45): pk01 -> word0 (keys 0,1 | 8,9), pk45 -> word2 (keys 4,5 | 12,13)
  //  swap(pk23, pk67): pk23 -> word1 (keys 2,3 |10,11), pk67 -> word3 (keys 6,7 | 14,15)
  auto pack8 = [&](const float* pp) -> short8 {
    unsigned wA, wB, wC, wD;
    asm("v_cvt_pk_bf16_f32 %0, %1, %2" : "=v"(wA) : "v"(pp[0]), "v"(pp[1]));
    asm("v_cvt_pk_bf16_f32 %0, %1, %2" : "=v"(wB) : "v"(pp[2]), "v"(pp[3]));
    asm("v_cvt_pk_bf16_f32 %0, %1, %2" : "=v"(wC) : "v"(pp[4]), "v"(pp[5]));
    asm("v_cvt_pk_bf16_f32 %0, %1, %2" : "=v"(wD) : "v"(pp[6]), "v"(pp[7]));
    asm("v_permlane32_swap_b32 %0, %1" : "+v"(wA), "+v"(wC));
    asm("v_permlane32_swap_b32 %0, %1" : "+v"(wB), "+v"(wD));
    int4v w4 = { (int)wA, (int)wB, (int)wC, (int)wD };
    return __builtin_bit_cast(short8, w4);
  };

  auto tile = [&](int kb, bool domask) {
    // S^T = K . Q^T  (rows=keys, cols=q)
    f32x16 sa = zero16();
#pragma unroll
    for (int s = 0; s < 4; s++) {
      short8 kf = *reinterpret_cast<const short8*>(
          &K[(size_t)(kb + l31) * (NKV * HD) + g * HD + s * 16 + hi8]);
      sa = __builtin_amdgcn_mfma_f32_32x32x16_bf16(kf, qf[s], sa, 0, 0, 0);
    }
    float p[16];
#pragma unroll
    for (int r = 0; r < 16; r++) p[r] = sa[r] * KLOG;
    if (domask) {
#pragma unroll
      for (int r = 0; r < 16; r++) {
        int kidx = kb + (r & 3) + 8 * (r >> 2) + hi4;
        bool ok = ((kidx <= qrow) && (kidx >= qrow - (WINDOW - 1))) || (kidx < NGLOB);
        p[r] = ok ? p[r] : -1e30f;
      }
    }
    // row max: in-lane tree + partner combine
    float t[16];
#pragma unroll
    for (int r = 0; r < 16; r++) t[r] = p[r];
#pragma unroll
    for (int st = 1; st < 16; st <<= 1)
#pragma unroll
      for (int i = 0; i < 16; i += 2 * st) t[i] = fmaxf(t[i], t[i + st]);
    float pmax = fmaxf(t[0], __shfl_xor(t[0], 32));
    // defer-max rescale
    if (!__all(pmax <= mrow + 8.0f)) {
      float mnew = fmaxf(mrow, pmax);
      float corr = exp2f(mrow - mnew);
      ssum *= corr;
#pragma unroll
      for (int r = 0; r < 16; r++) { o[0][r] *= corr; o[1][r] *= corr; }
      mrow = mnew;
    }
#pragma unroll
    for (int r = 0; r < 16; r++) p[r] = exp2f(p[r] - mrow);
    float su[16];
#pragma unroll
    for (int r = 0; r < 16; r++) su[r] = p[r];
#pragma unroll
    for (int st = 1; st < 16; st <<= 1)
#pragma unroll
      for (int i = 0; i < 16; i += 2 * st) su[i] += su[i + st];
    ssum += su[0];
    // P^T B-fragments (keys 0-15, 16-31)
    short8 pb0 = pack8(&p[0]);
    short8 pb1 = pack8(&p[8]);
    // O^T += V^T . P^T
#pragma unroll
    for (int ntl = 0; ntl < 2; ntl++) {
      const ushort* vp = &Vt[(size_t)(g * HD + ntl * 32 + l31) * T_SEQ + kb + hi8];
      short8 v0 = *reinterpret_cast<const short8*>(vp);
      short8 v1 = *reinterpret_cast<const short8*>(vp + 16);
      o[ntl] = __builtin_amdgcn_mfma_f32_32x32x16_bf16(v0, pb0, o[ntl], 0, 0, 0);
      o[ntl] = __builtin_amdgcn_mfma_f32_32x32x16_bf16(v1, pb1, o[ntl], 0, 0, 0);
    }
  };

  tile(0, true);                                       // global tokens (+ window overlap)
  int wsr = (q0 - (WINDOW - 1)) >> 5;
  int wstart = (wsr < 1) ? 32 : (wsr << 5);
  for (int kb = wstart; kb <= q0; kb += 32)
    tile(kb, (kb < q0 - 480) || (kb == q0));

  float stot = ssum + __shfl_xor(ssum, 32);
  float inv = 1.0f / stot;

  // epilogue: transpose O^T via LDS, coalesced bf16 writes
#pragma unroll
  for (int ntl = 0; ntl < 2; ntl++)
#pragma unroll
    for (int r = 0; r < 16; r++) {
      int dim = ntl * 32 + (r & 3) + 8 * (r >> 2) + hi4;
      Ot[wv][l31][dim] = f2bf(o[ntl][r] * inv);
    }
  __syncthreads();
  int qq = lane >> 1, hf = lane & 1;
#pragma unroll
  for (int c = 0; c < 4; c++) {
    short8 vv = *reinterpret_cast<const short8*>(&Ot[wv][qq][hf * 32 + c * 8]);
    *reinterpret_cast<short8*>(&Y[(size_t)(q0 + qq) * C_DIM + h * HD + hf * 32 + c * 8]) = vv;
  }
}

extern "C" void kernel_launch(void* const* d_in, const int* in_sizes, int n_in,
                              void* d_out, int out_size, void* d_ws, size_t ws_size,
                              hipStream_t stream) {
  const float* x  = (const float*)d_in[0];
  const float* fc = (const float*)d_in[1];
  const float* fs = (const float*)d_in[2];
  const float* wq = (const float*)d_in[3];
  const float* wk = (const float*)d_in[4];
  const float* wv = (const float*)d_in[5];
  const float* wo = (const float*)d_in[6];
  float* out = (float*)d_out;

  const size_t SZ_X = (size_t)T_SEQ * C_DIM;
  const size_t SZ_W = (size_t)(NKV * HD) * C_DIM;

  ushort* xb  = (ushort*)d_ws;
  ushort* wqb = xb  + SZ_X;
  ushort* wkb = wqb + SZ_X;
  ushort* wvb = wkb + SZ_W;
  ushort* wob = wvb + SZ_W;
  ushort* Qb  = wob + SZ_X;
  ushort* Kb  = Qb  + SZ_X;
  ushort* Vb  = Kb  + SZ_W;
  ushort* Vt  = Vb  + SZ_W;
  ushort* Yb  = Vt  + SZ_W;

  cvt_f32_bf16<<<512, 256, 0, stream>>>(x,  xb,  (int)(SZ_X / 8));
  cvt_f32_bf16<<<512, 256, 0, stream>>>(wq, wqb, (int)(SZ_X / 8));
  cvt_f32_bf16<<<256, 256, 0, stream>>>(wk, wkb, (int)(SZ_W / 8));
  cvt_f32_bf16<<<256, 256, 0, stream>>>(wv, wvb, (int)(SZ_W / 8));
  cvt_f32_bf16<<<512, 256, 0, stream>>>(wo, wob, (int)(SZ_X / 8));

  gemm2p<1><<<dim3(24, 16), 512, 0, stream>>>(xb, wqb, wkb, wvb, Qb, Kb, Vb, C_DIM);

  rope2<<<(T_SEQ * (NH + NKV) * 8) / 256, 256, 0, stream>>>(Qb, Kb, fc, fs);
  transpose_bf16<<<dim3((NKV * HD) / 64, T_SEQ / 64), 256, 0, stream>>>(Vb, Vt, T_SEQ, NKV * HD);

  attn32<<<512, 256, 0, stream>>>(Qb, Kb, Vt, Yb);

  gemm2p<0><<<dim3(16, 16), 512, 0, stream>>>(Yb, wob, nullptr, nullptr, out, nullptr, nullptr, C_DIM);
}

// Round 6
// 135.159 us; speedup vs baseline: 2.6826x; 1.0538x over previous
//
#include <hip/hip_runtime.h>
#include <hip/hip_bf16.h>

using short8 = __attribute__((ext_vector_type(8))) short;
using f32x4  = __attribute__((ext_vector_type(4))) float;
using f32x16 = __attribute__((ext_vector_type(16))) float;
using int4v  = __attribute__((ext_vector_type(4))) int;

#define T_SEQ  2048
#define C_DIM  2048
#define NH     32
#define NKV    8
#define HD     64
#define WINDOW 512
#define NGLOB  16

__device__ inline ushort f2bf(float f) {
  union { float f; unsigned u; } v; v.f = f;
  unsigned u = v.u;
  u += 0x7fffu + ((u >> 16) & 1u);
  return (ushort)(u >> 16);
}
__device__ inline float bf2f(ushort h) {
  union { unsigned u; float f; } v; v.u = ((unsigned)h) << 16;
  return v.f;
}

__device__ __forceinline__ void gl_lds16(const ushort* g, ushort* l) {
  __builtin_amdgcn_global_load_lds(
      (const __attribute__((address_space(1))) void*)g,
      (__attribute__((address_space(3))) void*)l, 16, 0, 0);
}

__device__ __forceinline__ f32x16 zero16() {
  f32x16 v;
#pragma unroll
  for (int i = 0; i < 16; i++) v[i] = 0.f;
  return v;
}

// One fused f32->bf16 convert over 5 segments (8 elems per chunk).
__global__ void cvt_all(const float* __restrict__ s0, ushort* __restrict__ d0, int n0,
                        const float* __restrict__ s1, ushort* __restrict__ d1, int n1,
                        const float* __restrict__ s2, ushort* __restrict__ d2, int n2,
                        const float* __restrict__ s3, ushort* __restrict__ d3, int n3,
                        const float* __restrict__ s4, ushort* __restrict__ d4, int n4) {
  int total = n0 + n1 + n2 + n3 + n4;
  int stride = gridDim.x * blockDim.x;
  for (int i = blockIdx.x * blockDim.x + threadIdx.x; i < total; i += stride) {
    int j = i; const float* s; ushort* d;
    if (j < n0) { s = s0; d = d0; }
    else { j -= n0;
      if (j < n1) { s = s1; d = d1; }
      else { j -= n1;
        if (j < n2) { s = s2; d = d2; }
        else { j -= n2;
          if (j < n3) { s = s3; d = d3; }
          else { j -= n3; s = s4; d = d4; } } } }
    f32x4 a = *reinterpret_cast<const f32x4*>(s + (size_t)j * 8);
    f32x4 b = *reinterpret_cast<const f32x4*>(s + (size_t)j * 8 + 4);
    short8 o;
#pragma unroll
    for (int k = 0; k < 4; k++) { o[k] = (short)f2bf(a[k]); o[4 + k] = (short)f2bf(b[k]); }
    *reinterpret_cast<short8*>(d + (size_t)j * 8) = o;
  }
}

// 2-phase double-buffered bf16 GEMM, C = A @ B^T. (unchanged)
template <int MODE>
__global__ __launch_bounds__(512) void gemm2p(const ushort* __restrict__ A,
                                              const ushort* __restrict__ B0,
                                              const ushort* __restrict__ B1,
                                              const ushort* __restrict__ B2,
                                              void* __restrict__ C0,
                                              void* __restrict__ C1,
                                              void* __restrict__ C2,
                                              int K) {
  __shared__ ushort As[2][2][128][32];
  __shared__ ushort Bs[2][2][128][32];
  const int tid  = threadIdx.x;
  const int lane = tid & 63;
  const int wid  = tid >> 6;
  const int wr = wid >> 2, wc = wid & 3;
  const int r16 = lane & 15, g16 = (lane >> 4) & 3;
  const int bx = blockIdx.x, by = blockIdx.y;

  const ushort* Brow;
  void* Cout;
  int ldc, col0;
  if constexpr (MODE == 1) {
    if (bx < 16)      { Brow = B0 + (size_t)bx * 128 * K;        Cout = C0; ldc = 2048; col0 = bx * 128; }
    else if (bx < 20) { Brow = B1 + (size_t)(bx - 16) * 128 * K; Cout = C1; ldc = 512;  col0 = (bx - 16) * 128; }
    else              { Brow = B2 + (size_t)(bx - 20) * 128 * K; Cout = C2; ldc = 512;  col0 = (bx - 20) * 128; }
  } else {
    Brow = B0 + (size_t)bx * 128 * K; Cout = C0; ldc = 2048; col0 = bx * 128;
  }
  const ushort* Arow = A + (size_t)by * 128 * K;

  f32x4 acc[4][2];
#pragma unroll
  for (int i = 0; i < 4; i++)
#pragma unroll
    for (int j = 0; j < 2; j++) acc[i][j] = (f32x4){0.f, 0.f, 0.f, 0.f};

  const int srow = tid >> 2, scch = tid & 3;
  const int ssc  = scch ^ ((srow >> 1) & 3);
  const size_t agoff = (size_t)srow * K + ssc * 8;
  const int rchunk = (g16 ^ ((r16 >> 1) & 3)) * 8;

  const int nt = K >> 6;
  int d = 0;

#define STAGE(dd, k0)                                                         \
  {                                                                           \
    _Pragma("unroll") for (int kk = 0; kk < 2; kk++) {                        \
      gl_lds16(&Arow[agoff + (k0) + kk * 32], &As[dd][kk][srow][scch * 8]);   \
      gl_lds16(&Brow[agoff + (k0) + kk * 32], &Bs[dd][kk][srow][scch * 8]);   \
    }                                                                         \
  }

  STAGE(0, 0);
  __syncthreads();

  for (int t = 0; t < nt; ++t) {
    if (t + 1 < nt) STAGE(d ^ 1, (t + 1) * 64);
#pragma unroll
    for (int kk = 0; kk < 2; kk++) {
      short8 af[4], bfv[2];
#pragma unroll
      for (int i = 0; i < 4; i++)
        af[i] = *reinterpret_cast<const short8*>(&As[d][kk][wr * 64 + i * 16 + r16][rchunk]);
#pragma unroll
      for (int j = 0; j < 2; j++)
        bfv[j] = *reinterpret_cast<const short8*>(&Bs[d][kk][wc * 32 + j * 16 + r16][rchunk]);
#pragma unroll
      for (int i = 0; i < 4; i++)
#pragma unroll
        for (int j = 0; j < 2; j++)
          acc[i][j] = __builtin_amdgcn_mfma_f32_16x16x32_bf16(af[i], bfv[j], acc[i][j], 0, 0, 0);
    }
    __syncthreads();
    d ^= 1;
  }
#undef STAGE

#pragma unroll
  for (int i = 0; i < 4; i++)
#pragma unroll
    for (int j = 0; j < 2; j++) {
      int col = col0 + wc * 32 + j * 16 + r16;
#pragma unroll
      for (int r = 0; r < 4; r++) {
        int row = by * 128 + wr * 64 + i * 16 + g16 * 4 + r;
        if constexpr (MODE == 0) ((float*)Cout)[(size_t)row * ldc + col] = acc[i][j][r];
        else                     ((ushort*)Cout)[(size_t)row * ldc + col] = f2bf(acc[i][j][r]);
      }
    }
}

// Fused RoPE for Q and K. Q additionally scaled by 0.125*log2(e) (softmax
// scale folded in; Q is only consumed by attention, which works in exp2 domain).
__global__ void rope2(ushort* __restrict__ Qb, ushort* __restrict__ Kb,
                      const float* __restrict__ fc, const float* __restrict__ fs) {
  int idx = blockIdx.x * blockDim.x + threadIdx.x;   // chunk id
  const int QN = T_SEQ * NH * 8;
  ushort* X; int t, hh, c, ld; float ksc;
  if (idx < QN) { X = Qb; c = idx & 7; hh = (idx >> 3) & 31; t = idx >> 8; ld = NH * HD;
                  ksc = 0.125f * 1.44269504089f; }
  else { idx -= QN; X = Kb; c = idx & 7; hh = (idx >> 3) & 7; t = idx >> 6; ld = NKV * HD;
         ksc = 1.0f; }
  size_t base = (size_t)t * ld + hh * HD + c * 8;
  short8 v = *reinterpret_cast<const short8*>(&X[base]);
  f32x4 cc = *reinterpret_cast<const f32x4*>(&fc[t * 32 + c * 4]);
  f32x4 ss = *reinterpret_cast<const f32x4*>(&fs[t * 32 + c * 4]);
  short8 o;
#pragma unroll
  for (int j = 0; j < 4; j++) {
    float x0 = bf2f((ushort)v[2 * j]), x1 = bf2f((ushort)v[2 * j + 1]);
    o[2 * j]     = (short)f2bf((x0 * cc[j] - x1 * ss[j]) * ksc);
    o[2 * j + 1] = (short)f2bf((x0 * ss[j] + x1 * cc[j]) * ksc);
  }
  *reinterpret_cast<short8*>(&X[base]) = o;
}

// out[c][r] = in[r][c], 64x64 LDS tiles, bf16.
__global__ __launch_bounds__(256) void transpose_bf16(const ushort* __restrict__ in,
                                                      ushort* __restrict__ out,
                                                      int R, int Cc) {
  __shared__ ushort tile[64][72];
  int tr = blockIdx.y * 64, tc = blockIdx.x * 64;
  int tid = threadIdx.x;
#pragma unroll
  for (int s = 0; s < 2; s++) {
    int idx = tid + s * 256;
    int row = idx >> 3, c8 = idx & 7;
    short8 v = *reinterpret_cast<const short8*>(&in[(size_t)(tr + row) * Cc + tc + c8 * 8]);
#pragma unroll
    for (int j = 0; j < 8; j++) tile[row][c8 * 8 + j] = (ushort)v[j];
  }
  __syncthreads();
#pragma unroll
  for (int s = 0; s < 2; s++) {
    int idx = tid + s * 256;
    int orow = idx >> 3, c8 = idx & 7;
    short8 v;
#pragma unroll
    for (int j = 0; j < 8; j++) v[j] = (short)tile[c8 * 8 + j][orow];
    *reinterpret_cast<short8*>(&out[(size_t)(tc + orow) * R + tr + c8 * 8]) = v;
  }
}

// Flash attention, swapped-operand 32x32 structure, register-prefetched K/V.
// Block = 4 waves = 4 q-heads of one kv-group at the SAME q-tile (shared K/V
// addresses -> L1 broadcast; uniform per-block work). S^T = K.Q^T (Q pre-scaled
// to log2 domain), O^T = V^T.P^T; key tiles of 32, next tile's K/V prefetched
// into registers while current tile computes.
__global__ __launch_bounds__(256) void attn32(const ushort* __restrict__ Q,
                                              const ushort* __restrict__ K,
                                              const ushort* __restrict__ Vt,
                                              ushort* __restrict__ Y) {
  __shared__ ushort Ot[4][32][72];
  const int lane = threadIdx.x & 63;
  const int wv   = threadIdx.x >> 6;
  const int g  = blockIdx.x >> 6;                    // kv group
  const int qt = blockIdx.x & 63;                    // q-tile
  const int h  = g * 4 + wv;                         // q-head
  const int q0 = qt << 5;
  const int l31 = lane & 31, hi = lane >> 5;
  const int hi8 = hi << 3, hi4 = hi << 2;
  const int qrow = q0 + l31;

  short8 qf[4];
#pragma unroll
  for (int s = 0; s < 4; s++)
    qf[s] = *reinterpret_cast<const short8*>(&Q[(size_t)qrow * C_DIM + h * HD + s * 16 + hi8]);

  f32x16 o[2] = { zero16(), zero16() };
  float mrow = -1e30f, ssum = 0.f;

  auto pack8 = [&](const float* pp) -> short8 {
    unsigned wA, wB, wC, wD;
    asm("v_cvt_pk_bf16_f32 %0, %1, %2" : "=v"(wA) : "v"(pp[0]), "v"(pp[1]));
    asm("v_cvt_pk_bf16_f32 %0, %1, %2" : "=v"(wB) : "v"(pp[2]), "v"(pp[3]));
    asm("v_cvt_pk_bf16_f32 %0, %1, %2" : "=v"(wC) : "v"(pp[4]), "v"(pp[5]));
    asm("v_cvt_pk_bf16_f32 %0, %1, %2" : "=v"(wD) : "v"(pp[6]), "v"(pp[7]));
    asm("v_permlane32_swap_b32 %0, %1" : "+v"(wA), "+v"(wC));
    asm("v_permlane32_swap_b32 %0, %1" : "+v"(wB), "+v"(wD));
    int4v w4 = { (int)wA, (int)wB, (int)wC, (int)wD };
    return __builtin_bit_cast(short8, w4);
  };

#define LOADKV(kreg, vreg, kb)                                                     \
  {                                                                                \
    _Pragma("unroll") for (int s = 0; s < 4; s++)                                  \
      kreg[s] = *reinterpret_cast<const short8*>(                                  \
          &K[(size_t)((kb) + l31) * (NKV * HD) + g * HD + s * 16 + hi8]);          \
    _Pragma("unroll") for (int ntl = 0; ntl < 2; ntl++) {                          \
      const ushort* vp = &Vt[(size_t)(g * HD + ntl * 32 + l31) * T_SEQ + (kb) + hi8]; \
      vreg[2 * ntl]     = *reinterpret_cast<const short8*>(vp);                    \
      vreg[2 * ntl + 1] = *reinterpret_cast<const short8*>(vp + 16);               \
    }                                                                              \
  }

#define PROCESS(kreg, vreg, kb, domask)                                            \
  {                                                                                \
    f32x16 sa = zero16();                                                          \
    __builtin_amdgcn_s_setprio(1);                                                 \
    _Pragma("unroll") for (int s = 0; s < 4; s++)                                  \
      sa = __builtin_amdgcn_mfma_f32_32x32x16_bf16(kreg[s], qf[s], sa, 0, 0, 0);   \
    __builtin_amdgcn_s_setprio(0);                                                 \
    float p[16];                                                                   \
    _Pragma("unroll") for (int r = 0; r < 16; r++) p[r] = sa[r];                   \
    if (domask) {                                                                  \
      _Pragma("unroll") for (int r = 0; r < 16; r++) {                             \
        int kidx = (kb) + (r & 3) + 8 * (r >> 2) + hi4;                            \
        bool ok = ((kidx <= qrow) && (kidx >= qrow - (WINDOW - 1))) || (kidx < NGLOB); \
        p[r] = ok ? p[r] : -1e30f;                                                 \
      }                                                                            \
    }                                                                              \
    float t[16];                                                                   \
    _Pragma("unroll") for (int r = 0; r < 16; r++) t[r] = p[r];                    \
    _Pragma("unroll") for (int st = 1; st < 16; st <<= 1)                          \
      _Pragma("unroll") for (int i2 = 0; i2 < 16; i2 += 2 * st)                    \
        t[i2] = fmaxf(t[i2], t[i2 + st]);                                          \
    float pmax = fmaxf(t[0], __shfl_xor(t[0], 32));                                \
    if (!__all(pmax <= mrow + 8.0f)) {                                             \
      float mnew = fmaxf(mrow, pmax);                                              \
      float corr = exp2f(mrow - mnew);                                             \
      ssum *= corr;                                                                \
      _Pragma("unroll") for (int r = 0; r < 16; r++) { o[0][r] *= corr; o[1][r] *= corr; } \
      mrow = mnew;                                                                 \
    }                                                                              \
    _Pragma("unroll") for (int r = 0; r < 16; r++) p[r] = exp2f(p[r] - mrow);      \
    float su[16];                                                                  \
    _Pragma("unroll") for (int r = 0; r < 16; r++) su[r] = p[r];                   \
    _Pragma("unroll") for (int st = 1; st < 16; st <<= 1)                          \
      _Pragma("unroll") for (int i2 = 0; i2 < 16; i2 += 2 * st)                    \
        su[i2] += su[i2 + st];                                                     \
    ssum += su[0];                                                                 \
    short8 pb0 = pack8(&p[0]);                                                     \
    short8 pb1 = pack8(&p[8]);                                                     \
    __builtin_amdgcn_s_setprio(1);                                                 \
    o[0] = __builtin_amdgcn_mfma_f32_32x32x16_bf16(vreg[0], pb0, o[0], 0, 0, 0);   \
    o[0] = __builtin_amdgcn_mfma_f32_32x32x16_bf16(vreg[1], pb1, o[0], 0, 0, 0);   \
    o[1] = __builtin_amdgcn_mfma_f32_32x32x16_bf16(vreg[2], pb0, o[1], 0, 0, 0);   \
    o[1] = __builtin_amdgcn_mfma_f32_32x32x16_bf16(vreg[3], pb1, o[1], 0, 0, 0);   \
    __builtin_amdgcn_s_setprio(0);                                                 \
  }

  // tile list: idx 0 -> kb=0 (global), idx i>=1 -> kb = wstart + (i-1)*32
  int wsr = (q0 - (WINDOW - 1)) >> 5;
  int wstart = (wsr < 1) ? 32 : (wsr << 5);
  int ntw = (q0 >= wstart) ? (((q0 - wstart) >> 5) + 1) : 0;
  const int NT = 1 + ntw;

  short8 kA[4], vA[4], kB[4], vB[4];
  LOADKV(kA, vA, 0);

  for (int i = 0; i < NT; i += 2) {
    int kb_i = (i == 0) ? 0 : wstart + (i - 1) * 32;
    if (i + 1 < NT) { int kb1 = wstart + i * 32; LOADKV(kB, vB, kb1); }
    bool m_i = (i == 0) || (kb_i < q0 - 480) || (kb_i == q0);
    PROCESS(kA, vA, kb_i, m_i);
    if (i + 1 < NT) {
      int kb1 = wstart + i * 32;
      if (i + 2 < NT) { int kb2 = wstart + (i + 1) * 32; LOADKV(kA, vA, kb2); }
      bool m1 = (kb1 < q0 - 480) || (kb1 == q0);
      PROCESS(kB, vB, kb1, m1);
    }
  }
#undef LOADKV
#undef PROCESS

  float stot = ssum + __shfl_xor(ssum, 32);
  float inv = 1.0f / stot;

#pragma unroll
  for (int ntl = 0; ntl < 2; ntl++)
#pragma unroll
    for (int r = 0; r < 16; r++) {
      int dim = ntl * 32 + (r & 3) + 8 * (r >> 2) + hi4;
      Ot[wv][l31][dim] = f2bf(o[ntl][r] * inv);
    }
  __syncthreads();
  int qq = lane >> 1, hf = lane & 1;
#pragma unroll
  for (int c = 0; c < 4; c++) {
    short8 vv = *reinterpret_cast<const short8*>(&Ot[wv][qq][hf * 32 + c * 8]);
    *reinterpret_cast<short8*>(&Y[(size_t)(q0 + qq) * C_DIM + h * HD + hf * 32 + c * 8]) = vv;
  }
}

extern "C" void kernel_launch(void* const* d_in, const int* in_sizes, int n_in,
                              void* d_out, int out_size, void* d_ws, size_t ws_size,
                              hipStream_t stream) {
  const float* x  = (const float*)d_in[0];
  const float* fc = (const float*)d_in[1];
  const float* fs = (const float*)d_in[2];
  const float* wq = (const float*)d_in[3];
  const float* wk = (const float*)d_in[4];
  const float* wv = (const float*)d_in[5];
  const float* wo = (const float*)d_in[6];
  float* out = (float*)d_out;

  const size_t SZ_X = (size_t)T_SEQ * C_DIM;
  const size_t SZ_W = (size_t)(NKV * HD) * C_DIM;

  ushort* xb  = (ushort*)d_ws;
  ushort* wqb = xb  + SZ_X;
  ushort* wkb = wqb + SZ_X;
  ushort* wvb = wkb + SZ_W;
  ushort* wob = wvb + SZ_W;
  ushort* Qb  = wob + SZ_X;
  ushort* Kb  = Qb  + SZ_X;
  ushort* Vb  = Kb  + SZ_W;
  ushort* Vt  = Vb  + SZ_W;
  ushort* Yb  = Vt  + SZ_W;

  cvt_all<<<1024, 256, 0, stream>>>(x,  xb,  (int)(SZ_X / 8),
                                    wq, wqb, (int)(SZ_X / 8),
                                    wk, wkb, (int)(SZ_W / 8),
                                    wv, wvb, (int)(SZ_W / 8),
                                    wo, wob, (int)(SZ_X / 8));

  gemm2p<1><<<dim3(24, 16), 512, 0, stream>>>(xb, wqb, wkb, wvb, Qb, Kb, Vb, C_DIM);

  rope2<<<(T_SEQ * (NH + NKV) * 8) / 256, 256, 0, stream>>>(Qb, Kb, fc, fs);
  transpose_bf16<<<dim3((NKV * HD) / 64, T_SEQ / 64), 256, 0, stream>>>(Vb, Vt, T_SEQ, NKV * HD);

  attn32<<<512, 256, 0, stream>>>(Qb, Kb, Vt, Yb);

  gemm2p<0><<<dim3(16, 16), 512, 0, stream>>>(Yb, wob, nullptr, nullptr, out, nullptr, nullptr, C_DIM);
}